// Round 12
// baseline (93.857 us; speedup 1.0000x reference)
//
#include <hip/hip_runtime.h>
#include <stdint.h>

#define CIN   64
#define COUT  64
#define HH    112
#define WW    112
#define NEXP  4
#define HW    (HH * WW)

typedef short bf16x8 __attribute__((ext_vector_type(8)));
typedef float f32x16 __attribute__((ext_vector_type(16)));

__device__ inline uint16_t f2bf(float f) {
    uint32_t u = __builtin_bit_cast(uint32_t, f);
    return (uint16_t)((u + 0x7FFFu + ((u >> 16) & 1u)) >> 16);
}

// async global->LDS, 16B per lane; LDS dest is wave-uniform base + lane*16.
__device__ __forceinline__ void gll16(const uint16_t* g, uint16_t* l) {
    __builtin_amdgcn_global_load_lds(
        (const __attribute__((address_space(1))) uint32_t*)g,
        (__attribute__((address_space(3))) uint32_t*)l, 16, 0, 0);
}

// ---------------------------------------------------------------------------
// Pass 1 (combined prep): blocks [0, B*114): x NCHW f32 -> Xt [B][114][114][64]
// bf16 zero-halo (memory-roofline transpose).  Blocks [B*114, ...): fold gates
// into per-sample weights Weff (bf16) + biases Beff (f32).
// Weff layout: [n][g=72][co=64][j=8], g = ((phase*9+khw)*2+kq)*2+par,
// ci = phase*32 + (kq*2+par)*8 + j.  co second-fastest -> A-frag load
// (lane&31 = co, 16B/lane) reads 512 contiguous bytes.
// ---------------------------------------------------------------------------
__global__ __launch_bounds__(256)
void prep(const float* __restrict__ x, const float* __restrict__ W,
          const float* __restrict__ bias, const float* __restrict__ mask,
          uint16_t* __restrict__ Xt, uint16_t* __restrict__ Weff,
          float* __restrict__ Beff, int B) {
    const int nxf = B * 114;
    if ((int)blockIdx.x < nxf) {
        __shared__ float lds[CIN][WW + 1];
        const int hp = blockIdx.x % 114;
        const int n  = blockIdx.x / 114;
        const int h  = hp - 1;
        uint16_t* orow = Xt + ((size_t)(n * 114 + hp)) * 114 * 64;

        if (h < 0 || h >= HH) {
            const uint4 z = {0, 0, 0, 0};
            for (int u = threadIdx.x; u < 114 * 8; u += 256)
                *(uint4*)(orow + u * 8) = z;
            return;
        }
        for (int i = threadIdx.x; i < CIN * WW; i += 256) {
            int ci = i / WW, w = i % WW;
            lds[ci][w] = x[((size_t)(n * CIN + ci)) * HW + h * WW + w];
        }
        __syncthreads();
        for (int u = threadIdx.x; u < 114 * 8; u += 256) {
            int wp = u >> 3, cg = u & 7;
            int w = wp - 1;
            union { uint16_t s[8]; uint4 v; } pk;
            if (w < 0 || w >= WW) {
                pk.v = (uint4){0, 0, 0, 0};
            } else {
#pragma unroll
                for (int j = 0; j < 8; ++j) pk.s[j] = f2bf(lds[cg * 8 + j][w]);
            }
            *(uint4*)(orow + (size_t)u * 8) = pk.v;
        }
    } else {
        int idx = (blockIdx.x - nxf) * 256 + threadIdx.x;
        if (idx >= B * 72 * 512) return;
        int j   = idx & 7;
        int co  = (idx >> 3) & 63;
        int g   = (idx >> 9) % 72;
        int n   = idx / (512 * 72);
        int par   = g & 1;
        int kq    = (g >> 1) & 1;
        int khw   = (g >> 2) % 9;
        int phase = (g >> 2) / 9;
        int ci = phase * 32 + (kq * 2 + par) * 8 + j;
        float acc = 0.f;
#pragma unroll
        for (int e = 0; e < NEXP; ++e)
            acc = fmaf(mask[n * NEXP + e],
                       W[((size_t)(e * COUT + co) * CIN + ci) * 9 + khw], acc);
        Weff[idx] = f2bf(acc);
        if (g == 0 && j == 0) {
            float ba = 0.f;
#pragma unroll
            for (int e = 0; e < NEXP; ++e)
                ba = fmaf(mask[n * NEXP + e], bias[e * COUT + co], ba);
            Beff[n * COUT + co] = ba;
        }
    }
}

// ---------------------------------------------------------------------------
// Pass 2: conv.  8x16 pixel tile, 256 thr (4 waves), grid B*98 = 3136.
// KEY CHANGE vs R9/R11: each wave owns 32 pixels (2 rows x 16 cols) x 64 co
// -> only TWO f32x16 accumulators (32 regs).  The 4-acc variants carried
// ~132 unified VGPR+acc regs -> hard 3-wave/SIMD ceiling (measured occupancy
// 22-32% across R8-R11).  With 32-reg acc + launch_bounds(256,6) the
// allocator targets 6 waves/SIMD -> 2x latency-hiding pool.
// Staging: phase-split (2 x 32ci), halo [10 rows][18 cols] -> 720 16B units,
// LDS 11520B [pix][32ci], swizzle on SOURCE addr: slot s holds octet
// s ^ ((pix>>1)&3)  (byte-identical read scheme to R9).
// NOTE: acc regs halved is what makes min-waves=6 safe; with 64-reg acc a
// cap this low spilled catastrophically (round-4: 1.77GB scratch, 7x).
// ---------------------------------------------------------------------------
__global__ __launch_bounds__(256, 6)
void conv_gll(const uint16_t* __restrict__ Xt, const uint16_t* __restrict__ Weff,
              const float* __restrict__ Beff, float* __restrict__ out,
              int nwg) {
    __shared__ uint16_t ldsx[720 * 8];   // 11520 B: [180 pix][32 ci]

    // T1 XCD swizzle (nwg = 3136 % 8 == 0): a sample's 98 blocks share one
    // XCD's L2 copy of its 72KB weights + Xt slice.
    int bid = blockIdx.x;
    if ((nwg & 7) == 0)
        bid = (bid & 7) * (nwg >> 3) + (bid >> 3);

    const int tid  = threadIdx.x;
    const int lane = tid & 63;
    const int wid  = tid >> 6;
    const int tileIdx = bid % 98;
    const int n  = bid / 98;
    const int th = tileIdx / 7, tw = tileIdx % 7;
    const int h0 = th * 8, w0 = tw * 16;

    const uint16_t* xt_n = Xt + (size_t)n * (114 * 114 * 64);

    const int rowb = wid * 2 + ((lane & 31) >> 4); // pixel row 0..7
    const int colb = lane & 15;                    // pixel col 0..15
    const int par  = lane >> 5;                    // k-octet parity

    const uint16_t* wbase = Weff + (size_t)n * 36864
                          + (size_t)par * 512 + (size_t)(lane & 31) * 8;

    f32x16 acc0 = {}, acc1 = {};

#pragma unroll
    for (int phase = 0; phase < 2; ++phase) {
        if (phase) __syncthreads();   // phase-0 reads done before overwrite
        // ---- stage 720 units: 2 x gll + 208-thread gll tail
#pragma unroll
        for (int it = 0; it < 2; ++it) {
            int v = it * 256 + tid;
            int pix = v >> 2, s = v & 3;
            int dh = pix / 18, dw = pix - dh * 18;
            int o = s ^ ((pix >> 1) & 3);
            const uint16_t* src = xt_n
                + ((size_t)(h0 + dh) * 114 + (w0 + dw)) * 64 + phase * 32 + o * 8;
            gll16(src, ldsx + (size_t)(it * 256 + wid * 64) * 8);
        }
        if (tid < 208) {   // units 512..719 (waves 0-2 full, wave 3 lanes 0-15)
            int v = 512 + tid;
            int pix = v >> 2, s = v & 3;
            int dh = pix / 18, dw = pix - dh * 18;
            int o = s ^ ((pix >> 1) & 3);
            const uint16_t* src = xt_n
                + ((size_t)(h0 + dh) * 114 + (w0 + dw)) * 64 + phase * 32 + o * 8;
            gll16(src, ldsx + (size_t)(512 + wid * 64) * 8);
        }
        __syncthreads();   // drains vmcnt before any wave reads the tile

        const uint16_t* wp = wbase + (size_t)phase * 36 * 512;
#pragma unroll 2
        for (int khw = 0; khw < 9; ++khw) {
            const int dh = khw / 3;
            const int dw = khw - dh * 3;
            const int pb = (rowb + dh) * 18 + (colb + dw);
            const int f  = (pb >> 1) & 3;
            const uint16_t* lp = &ldsx[pb * 32];
#pragma unroll
            for (int kq = 0; kq < 2; ++kq) {
                const int cgA = kq * 2 + par;
                bf16x8 b0 = *(const bf16x8*)(lp + ((cgA ^ f) << 3));
                const uint16_t* wk = wp + (size_t)((khw * 2 + kq) * 2) * 512;
                bf16x8 a0 = *(const bf16x8*)(wk);
                bf16x8 a1 = *(const bf16x8*)(wk + 256);   // co+32
                acc0 = __builtin_amdgcn_mfma_f32_32x32x16_bf16(a0, b0, acc0, 0, 0, 0);
                acc1 = __builtin_amdgcn_mfma_f32_32x32x16_bf16(a1, b0, acc1, 0, 0, 0);
            }
        }
    }

    // ---- epilogue: C/D col=lane&31 (pixel), row=(r&3)+8*(r>>2)+4*par
    const float* bptr = Beff + n * 64;
    const int row0 = h0 + rowb;
    const int col  = w0 + colb;
#pragma unroll
    for (int r = 0; r < 16; ++r) {
        const int co = (r & 3) + 8 * (r >> 2) + 4 * par;
        size_t o0 = ((size_t)(n * COUT + co) * HH + row0) * WW + col;
        __builtin_nontemporal_store(acc0[r] + bptr[co], &out[o0]);
        __builtin_nontemporal_store(acc1[r] + bptr[co + 32],
                                    &out[o0 + (size_t)32 * HW]);
    }
}

// ---------------------------------------------------------------------------
// Fallback (round-1 path): per-sample folded weights, fp32 vector conv.
// ---------------------------------------------------------------------------
#define COB   8
#define PIX_PER_BLK 256
#define NTILE (HW / PIX_PER_BLK)

__global__ void fold_weights(const float* __restrict__ W,
                             const float* __restrict__ mask,
                             float* __restrict__ Weff, int B) {
    int idx = blockIdx.x * blockDim.x + threadIdx.x;
    int total = B * CIN * 9 * COUT;
    if (idx >= total) return;
    int co = idx % COUT;
    int t  = idx / COUT;
    int k  = t % 9;
    t /= 9;
    int ci = t % CIN;
    int n  = t / CIN;
    float acc = 0.f;
#pragma unroll
    for (int e = 0; e < NEXP; ++e)
        acc = fmaf(mask[n * NEXP + e],
                   W[(((size_t)(e * COUT + co) * CIN + ci) * 9) + k], acc);
    Weff[idx] = acc;
}

__global__ __launch_bounds__(PIX_PER_BLK, 4)
void conv_gated(const float* __restrict__ x,
                const float* __restrict__ mask,
                const float* __restrict__ bias,
                const float* __restrict__ Weff,
                float* __restrict__ out) {
    const int tile = blockIdx.x % NTILE;
    const int cob  = (blockIdx.x / NTILE) % (COUT / COB);
    const int n    = blockIdx.x / (NTILE * (COUT / COB));
    const int p = tile * PIX_PER_BLK + threadIdx.x;
    const int h = p / WW;
    const int w = p % WW;
    const int co0 = cob * COB;

    float acc[COB];
#pragma unroll
    for (int j = 0; j < COB; ++j) {
        float a = 0.f;
#pragma unroll
        for (int e = 0; e < NEXP; ++e)
            a = fmaf(mask[n * NEXP + e], bias[e * COUT + co0 + j], a);
        acc[j] = a;
    }

    const float* xb = x + (((size_t)n * CIN) * HH + h) * WW + w;
    const float* wb = Weff + ((size_t)n * CIN) * 9 * COUT + co0;
    const bool rok0 = (h > 0), rok2 = (h < HH - 1);
    const bool cok0 = (w > 0), cok2 = (w < WW - 1);

    for (int ci = 0; ci < CIN; ++ci) {
        const float* xc = xb + (size_t)ci * HW;
        const float* wc = wb + (size_t)ci * 9 * COUT;
#pragma unroll
        for (int kh = 0; kh < 3; ++kh) {
            const bool rok = (kh == 0) ? rok0 : ((kh == 2) ? rok2 : true);
#pragma unroll
            for (int kw = 0; kw < 3; ++kw) {
                const bool cok = (kw == 0) ? cok0 : ((kw == 2) ? cok2 : true);
                float xv = (rok && cok) ? xc[(kh - 1) * WW + (kw - 1)] : 0.f;
                const float4* wk = (const float4*)(wc + (kh * 3 + kw) * COUT);
                float4 wa = wk[0], wb4 = wk[1];
                acc[0] = fmaf(xv, wa.x, acc[0]);
                acc[1] = fmaf(xv, wa.y, acc[1]);
                acc[2] = fmaf(xv, wa.z, acc[2]);
                acc[3] = fmaf(xv, wa.w, acc[3]);
                acc[4] = fmaf(xv, wb4.x, acc[4]);
                acc[5] = fmaf(xv, wb4.y, acc[5]);
                acc[6] = fmaf(xv, wb4.z, acc[6]);
                acc[7] = fmaf(xv, wb4.w, acc[7]);
            }
        }
    }
    float* ob = out + (((size_t)(n * COUT + co0)) * HH + h) * WW + w;
#pragma unroll
    for (int j = 0; j < COB; ++j)
        ob[(size_t)j * HW] = acc[j];
}

// ---------------------------------------------------------------------------
extern "C" void kernel_launch(void* const* d_in, const int* in_sizes, int n_in,
                              void* d_out, int out_size, void* d_ws, size_t ws_size,
                              hipStream_t stream) {
    const float* x    = (const float*)d_in[0];
    const float* mask = (const float*)d_in[1];
    const float* W    = (const float*)d_in[2];
    const float* b    = (const float*)d_in[3];
    float* out = (float*)d_out;

    const int B = in_sizes[0] / (CIN * HW);
    const size_t weffB = (size_t)B * 36864 * 2;
    const size_t beffB = (size_t)B * COUT * 4;
    const size_t xtB   = (size_t)B * 114 * 114 * 64 * 2;
    const size_t need  = weffB + beffB + xtB;

    if (ws_size >= need) {
        uint16_t* Weff = (uint16_t*)d_ws;
        float*    Beff = (float*)((char*)d_ws + weffB);
        uint16_t* Xt   = (uint16_t*)((char*)d_ws + weffB + beffB);
        int foldBlocks = (B * 72 * 512 + 255) / 256;
        prep<<<B * 114 + foldBlocks, 256, 0, stream>>>(x, W, b, mask,
                                                       Xt, Weff, Beff, B);
        const int nwg = B * 98;
        conv_gll<<<nwg, 256, 0, stream>>>(Xt, Weff, Beff, out, nwg);
    } else {
        float* Weff = (float*)d_ws;
        const size_t weff_elems = (size_t)B * CIN * 9 * COUT;
        int foldBlocks = (int)((weff_elems + 255) / 256);
        fold_weights<<<foldBlocks, 256, 0, stream>>>(W, mask, Weff, B);
        conv_gated<<<B * (COUT / COB) * NTILE, PIX_PER_BLK, 0, stream>>>(
            x, mask, b, Weff, out);
    }
}

// Round 13
// 82.491 us; speedup vs baseline: 1.1378x; 1.1378x over previous
//
#include <hip/hip_runtime.h>
#include <stdint.h>

#define CIN   64
#define COUT  64
#define HH    112
#define WW    112
#define NEXP  4
#define HW    (HH * WW)

typedef short bf16x8 __attribute__((ext_vector_type(8)));
typedef float f32x16 __attribute__((ext_vector_type(16)));

__device__ inline uint16_t f2bf(float f) {
    uint32_t u = __builtin_bit_cast(uint32_t, f);
    return (uint16_t)((u + 0x7FFFu + ((u >> 16) & 1u)) >> 16);
}

// async global->LDS, 16B per lane; LDS dest is wave-uniform base + lane*16.
__device__ __forceinline__ void gll16(const uint16_t* g, uint16_t* l) {
    __builtin_amdgcn_global_load_lds(
        (const __attribute__((address_space(1))) uint32_t*)g,
        (__attribute__((address_space(3))) uint32_t*)l, 16, 0, 0);
}

// ---------------------------------------------------------------------------
// Pass 1 (combined prep): blocks [0, B*114): x NCHW f32 -> Xt [B][114][114][64]
// bf16 zero-halo (memory-roofline transpose).  Blocks [B*114, ...): fold gates
// into per-sample weights Weff (bf16) + biases Beff (f32).
// Weff layout: [n][g=72][co=64][j=8], g = ((phase*9+khw)*2+kq)*2+par,
// ci = phase*32 + (kq*2+par)*8 + j.  co second-fastest -> A-frag load
// (lane&31 = co, 16B/lane) reads 512 contiguous bytes.
// ---------------------------------------------------------------------------
__global__ __launch_bounds__(256)
void prep(const float* __restrict__ x, const float* __restrict__ W,
          const float* __restrict__ bias, const float* __restrict__ mask,
          uint16_t* __restrict__ Xt, uint16_t* __restrict__ Weff,
          float* __restrict__ Beff, int B) {
    const int nxf = B * 114;
    if ((int)blockIdx.x < nxf) {
        __shared__ float lds[CIN][WW + 1];
        const int hp = blockIdx.x % 114;
        const int n  = blockIdx.x / 114;
        const int h  = hp - 1;
        uint16_t* orow = Xt + ((size_t)(n * 114 + hp)) * 114 * 64;

        if (h < 0 || h >= HH) {
            const uint4 z = {0, 0, 0, 0};
            for (int u = threadIdx.x; u < 114 * 8; u += 256)
                *(uint4*)(orow + u * 8) = z;
            return;
        }
        for (int i = threadIdx.x; i < CIN * WW; i += 256) {
            int ci = i / WW, w = i % WW;
            lds[ci][w] = x[((size_t)(n * CIN + ci)) * HW + h * WW + w];
        }
        __syncthreads();
        for (int u = threadIdx.x; u < 114 * 8; u += 256) {
            int wp = u >> 3, cg = u & 7;
            int w = wp - 1;
            union { uint16_t s[8]; uint4 v; } pk;
            if (w < 0 || w >= WW) {
                pk.v = (uint4){0, 0, 0, 0};
            } else {
#pragma unroll
                for (int j = 0; j < 8; ++j) pk.s[j] = f2bf(lds[cg * 8 + j][w]);
            }
            *(uint4*)(orow + (size_t)u * 8) = pk.v;
        }
    } else {
        int idx = (blockIdx.x - nxf) * 256 + threadIdx.x;
        if (idx >= B * 72 * 512) return;
        int j   = idx & 7;
        int co  = (idx >> 3) & 63;
        int g   = (idx >> 9) % 72;
        int n   = idx / (512 * 72);
        int par   = g & 1;
        int kq    = (g >> 1) & 1;
        int khw   = (g >> 2) % 9;
        int phase = (g >> 2) / 9;
        int ci = phase * 32 + (kq * 2 + par) * 8 + j;
        float acc = 0.f;
#pragma unroll
        for (int e = 0; e < NEXP; ++e)
            acc = fmaf(mask[n * NEXP + e],
                       W[((size_t)(e * COUT + co) * CIN + ci) * 9 + khw], acc);
        Weff[idx] = f2bf(acc);
        if (g == 0 && j == 0) {
            float ba = 0.f;
#pragma unroll
            for (int e = 0; e < NEXP; ++e)
                ba = fmaf(mask[n * NEXP + e], bias[e * COUT + co], ba);
            Beff[n * COUT + co] = ba;
        }
    }
}

// ---------------------------------------------------------------------------
// Pass 2: conv.  ONE WAVE PER BLOCK (64 thr), 4x16 pixel tile, all 64 cout:
// per-wave geometry identical to the traffic-optimal R9 wave (64 px x 64 co,
// 4 accs, 72 A-loads, 72 B-reads, 288 MFMA) but the stall domain is now a
// single wave: no inter-wave barrier coupling, each wave drains only its own
// staging, and ~12 independent resident waves/CU hide each other's latency.
// (R12 showed the alternative -- smaller acc, more waves -- doubles A/halo
// traffic: total A-reads scale as 1/P.  Keep P=64, shrink the block instead.)
// Staging per ci-half phase: halo [6 rows][18 cols] x 32ci = 432 16B units,
// LDS 6912B [pix][32ci], swizzle on SOURCE addr: slot s holds octet
// s ^ ((pix>>1)&3)  (byte-identical read scheme to R9).
// NOTE: min-waves must stay <=3: 64 acc VGPRs in the unified file; a lower
// cap spills accs (round-4: 1.77GB scratch traffic, 7x regression).
// ---------------------------------------------------------------------------
__global__ __launch_bounds__(64, 3)
void conv_1w(const uint16_t* __restrict__ Xt, const uint16_t* __restrict__ Weff,
             const float* __restrict__ Beff, float* __restrict__ out,
             int nwg) {
    __shared__ uint16_t ldsx[432 * 8];   // 6912 B: [108 pix][32 ci]

    // T1 XCD swizzle (nwg = 6272 % 8 == 0): a sample's 196 blocks share one
    // XCD's L2 copy of its 72KB weights + Xt slice.
    int bid = blockIdx.x;
    if ((nwg & 7) == 0)
        bid = (bid & 7) * (nwg >> 3) + (bid >> 3);

    const int lane = threadIdx.x;          // 0..63 (one wave)
    const int tileIdx = bid % 196;
    const int n  = bid / 196;
    const int th = tileIdx / 7, tw = tileIdx % 7;
    const int h0 = th * 4, w0 = tw * 16;

    const uint16_t* xt_n = Xt + (size_t)n * (114 * 114 * 64);

    const int rowb = (lane & 31) >> 4;     // pixel row 0..1 (nf0)
    const int colb = lane & 15;            // pixel col 0..15
    const int par  = lane >> 5;            // k-octet parity

    const uint16_t* wbase = Weff + (size_t)n * 36864
                          + (size_t)par * 512 + (size_t)(lane & 31) * 8;

    f32x16 acc00 = {}, acc01 = {}, acc10 = {}, acc11 = {};

#pragma unroll
    for (int phase = 0; phase < 2; ++phase) {
        if (phase) __syncthreads();   // 1-wave: just the waitcnt ordering
        // ---- stage 432 units: 6 full gll rounds + 48-lane round
#pragma unroll
        for (int it = 0; it < 7; ++it) {
            int v = it * 64 + lane;
            if (it < 6 || lane < 48) {
                int pix = v >> 2, s = v & 3;
                int dh = pix / 18, dw = pix - dh * 18;
                int o = s ^ ((pix >> 1) & 3);
                const uint16_t* src = xt_n
                    + ((size_t)(h0 + dh) * 114 + (w0 + dw)) * 64
                    + phase * 32 + o * 8;
                gll16(src, ldsx + (size_t)(it * 64) * 8);
            }
        }
        __syncthreads();   // drains vmcnt before reads (1-wave: no HW barrier cost)

        const uint16_t* wp = wbase + (size_t)phase * 36 * 512;
#pragma unroll 3
        for (int khw = 0; khw < 9; ++khw) {
            const int dh = khw / 3;
            const int dw = khw - dh * 3;
            const int pb0 = (rowb + dh) * 18 + (colb + dw);
            const int pb1 = pb0 + 36;              // nf=1: +2 pixel rows
            const int f0 = (pb0 >> 1) & 3, f1 = (pb1 >> 1) & 3;
            const uint16_t* lp0 = &ldsx[pb0 * 32];
            const uint16_t* lp1 = &ldsx[pb1 * 32];
#pragma unroll
            for (int kq = 0; kq < 2; ++kq) {
                const int cgA = kq * 2 + par;
                bf16x8 b0 = *(const bf16x8*)(lp0 + ((cgA ^ f0) << 3));
                bf16x8 b1 = *(const bf16x8*)(lp1 + ((cgA ^ f1) << 3));
                const uint16_t* wk = wp + (size_t)((khw * 2 + kq) * 2) * 512;
                bf16x8 a0 = *(const bf16x8*)(wk);
                bf16x8 a1 = *(const bf16x8*)(wk + 256);   // co+32
                acc00 = __builtin_amdgcn_mfma_f32_32x32x16_bf16(a0, b0, acc00, 0, 0, 0);
                acc01 = __builtin_amdgcn_mfma_f32_32x32x16_bf16(a0, b1, acc01, 0, 0, 0);
                acc10 = __builtin_amdgcn_mfma_f32_32x32x16_bf16(a1, b0, acc10, 0, 0, 0);
                acc11 = __builtin_amdgcn_mfma_f32_32x32x16_bf16(a1, b1, acc11, 0, 0, 0);
            }
        }
    }

    // ---- epilogue: C/D col=lane&31 (pixel), row=(r&3)+8*(r>>2)+4*par
    const float* bptr = Beff + n * 64;
    const int row0 = h0 + rowb;
    const int col  = w0 + colb;
#pragma unroll
    for (int r = 0; r < 16; ++r) {
        const int co = (r & 3) + 8 * (r >> 2) + 4 * par;
        const float bia0 = bptr[co];
        const float bia1 = bptr[co + 32];
        size_t o00 = ((size_t)(n * COUT + co) * HH + row0) * WW + col;
        __builtin_nontemporal_store(acc00[r] + bia0, &out[o00]);
        __builtin_nontemporal_store(acc01[r] + bia0, &out[o00 + 2 * WW]);
        size_t o10 = o00 + (size_t)32 * HW;
        __builtin_nontemporal_store(acc10[r] + bia1, &out[o10]);
        __builtin_nontemporal_store(acc11[r] + bia1, &out[o10 + 2 * WW]);
    }
}

// ---------------------------------------------------------------------------
// Fallback (round-1 path): per-sample folded weights, fp32 vector conv.
// ---------------------------------------------------------------------------
#define COB   8
#define PIX_PER_BLK 256
#define NTILE (HW / PIX_PER_BLK)

__global__ void fold_weights(const float* __restrict__ W,
                             const float* __restrict__ mask,
                             float* __restrict__ Weff, int B) {
    int idx = blockIdx.x * blockDim.x + threadIdx.x;
    int total = B * CIN * 9 * COUT;
    if (idx >= total) return;
    int co = idx % COUT;
    int t  = idx / COUT;
    int k  = t % 9;
    t /= 9;
    int ci = t % CIN;
    int n  = t / CIN;
    float acc = 0.f;
#pragma unroll
    for (int e = 0; e < NEXP; ++e)
        acc = fmaf(mask[n * NEXP + e],
                   W[(((size_t)(e * COUT + co) * CIN + ci) * 9) + k], acc);
    Weff[idx] = acc;
}

__global__ __launch_bounds__(PIX_PER_BLK, 4)
void conv_gated(const float* __restrict__ x,
                const float* __restrict__ mask,
                const float* __restrict__ bias,
                const float* __restrict__ Weff,
                float* __restrict__ out) {
    const int tile = blockIdx.x % NTILE;
    const int cob  = (blockIdx.x / NTILE) % (COUT / COB);
    const int n    = blockIdx.x / (NTILE * (COUT / COB));
    const int p = tile * PIX_PER_BLK + threadIdx.x;
    const int h = p / WW;
    const int w = p % WW;
    const int co0 = cob * COB;

    float acc[COB];
#pragma unroll
    for (int j = 0; j < COB; ++j) {
        float a = 0.f;
#pragma unroll
        for (int e = 0; e < NEXP; ++e)
            a = fmaf(mask[n * NEXP + e], bias[e * COUT + co0 + j], a);
        acc[j] = a;
    }

    const float* xb = x + (((size_t)n * CIN) * HH + h) * WW + w;
    const float* wb = Weff + ((size_t)n * CIN) * 9 * COUT + co0;
    const bool rok0 = (h > 0), rok2 = (h < HH - 1);
    const bool cok0 = (w > 0), cok2 = (w < WW - 1);

    for (int ci = 0; ci < CIN; ++ci) {
        const float* xc = xb + (size_t)ci * HW;
        const float* wc = wb + (size_t)ci * 9 * COUT;
#pragma unroll
        for (int kh = 0; kh < 3; ++kh) {
            const bool rok = (kh == 0) ? rok0 : ((kh == 2) ? rok2 : true);
#pragma unroll
            for (int kw = 0; kw < 3; ++kw) {
                const bool cok = (kw == 0) ? cok0 : ((kw == 2) ? cok2 : true);
                float xv = (rok && cok) ? xc[(kh - 1) * WW + (kw - 1)] : 0.f;
                const float4* wk = (const float4*)(wc + (kh * 3 + kw) * COUT);
                float4 wa = wk[0], wb4 = wk[1];
                acc[0] = fmaf(xv, wa.x, acc[0]);
                acc[1] = fmaf(xv, wa.y, acc[1]);
                acc[2] = fmaf(xv, wa.z, acc[2]);
                acc[3] = fmaf(xv, wa.w, acc[3]);
                acc[4] = fmaf(xv, wb4.x, acc[4]);
                acc[5] = fmaf(xv, wb4.y, acc[5]);
                acc[6] = fmaf(xv, wb4.z, acc[6]);
                acc[7] = fmaf(xv, wb4.w, acc[7]);
            }
        }
    }
    float* ob = out + (((size_t)(n * COUT + co0)) * HH + h) * WW + w;
#pragma unroll
    for (int j = 0; j < COB; ++j)
        ob[(size_t)j * HW] = acc[j];
}

// ---------------------------------------------------------------------------
extern "C" void kernel_launch(void* const* d_in, const int* in_sizes, int n_in,
                              void* d_out, int out_size, void* d_ws, size_t ws_size,
                              hipStream_t stream) {
    const float* x    = (const float*)d_in[0];
    const float* mask = (const float*)d_in[1];
    const float* W    = (const float*)d_in[2];
    const float* b    = (const float*)d_in[3];
    float* out = (float*)d_out;

    const int B = in_sizes[0] / (CIN * HW);
    const size_t weffB = (size_t)B * 36864 * 2;
    const size_t beffB = (size_t)B * COUT * 4;
    const size_t xtB   = (size_t)B * 114 * 114 * 64 * 2;
    const size_t need  = weffB + beffB + xtB;

    if (ws_size >= need) {
        uint16_t* Weff = (uint16_t*)d_ws;
        float*    Beff = (float*)((char*)d_ws + weffB);
        uint16_t* Xt   = (uint16_t*)((char*)d_ws + weffB + beffB);
        int foldBlocks = (B * 72 * 512 + 255) / 256;
        prep<<<B * 114 + foldBlocks, 256, 0, stream>>>(x, W, b, mask,
                                                       Xt, Weff, Beff, B);
        const int nwg = B * 196;
        conv_1w<<<nwg, 64, 0, stream>>>(Xt, Weff, Beff, out, nwg);
    } else {
        float* Weff = (float*)d_ws;
        const size_t weff_elems = (size_t)B * CIN * 9 * COUT;
        int foldBlocks = (int)((weff_elems + 255) / 256);
        fold_weights<<<foldBlocks, 256, 0, stream>>>(W, mask, Weff, B);
        conv_gated<<<B * (COUT / COB) * NTILE, PIX_PER_BLK, 0, stream>>>(
            x, mask, b, Weff, out);
    }
}